// Round 3
// baseline (250.384 us; speedup 1.0000x reference)
//
#include <hip/hip_runtime.h>

// Net_18966575579675: 722 tiny MLPs (11->10->10->6), B=8192, fp32.
// R7: spill elimination. R4-R6 showed occupancy pinned at 29.5% invariant
// to grid (3x), LDS (/2) and barrier semantics. Register math: the SUB=4
// unrolled body needs ~140 live VGPRs (cam 40 + h1 40 + h2 40 + pr/prn 8)
// but rocprof reports 72 -> the compiler is spilling to scratch. Scratch
// backing caps resident waves (the occupancy pin), and per-chunk scratch
// reloads are the ~24k-cycle/chunk stall. The 12-15KB unrolled body also
// thrashes I$ across out-of-phase blocks.
// Fix: roll the SUB loop (one row-MLP per iteration, inner loops still
// unrolled -> all reg-array indices static), camera 40 VGPRs -> 10KB LDS
// tile [10][256] staged once per block, prior via cndmask chain. Live set
// ~55 VGPRs, zero scratch, ~2.5KB loop body.

#define NN 722
#define CAMD 10
#define HD 10
#define LODD 6
#define ROWF (NN * LODD)       // 4332 floats per output row
#define SUB 4                  // batch sub-tiles (rows = SUB*64)
#define BT 256                 // batch rows per block
#define NETS_PER_CHUNK 4       // one net per wave
#define NCHUNKS 181            // ceil(722/4); last chunk has 2 nets
#define CPG 2                  // chunks per y-group
#define NGROUPS 91             // 91*2 = 182 slots >= 181 chunks
#define LSTRIDE 25             // 24 floats + 1 pad (odd -> conflict-free)
#define HROWS 128              // rows staged per flush pass

// LDS-only barrier: order ds ops across waves WITHOUT draining vmcnt
// (global stores / prefetch loads stay in flight).
__device__ __forceinline__ void lds_barrier() {
    asm volatile("s_waitcnt lgkmcnt(0)" ::: "memory");
    __builtin_amdgcn_s_barrier();
}

__global__ __launch_bounds__(256) void Net_18966575579675_kernel(
    const float* __restrict__ prior, const float* __restrict__ camera,
    const float* __restrict__ W1, const float* __restrict__ b1,
    const float* __restrict__ W2, const float* __restrict__ b2,
    const float* __restrict__ W3, const float* __restrict__ b3,
    float* __restrict__ out)
{
    const int tid  = threadIdx.x;
    const int lane = tid & 63;
    // Wave-uniform wave id -> net index -> weight fetches scalarize to s_load.
    const int wave = __builtin_amdgcn_readfirstlane(tid >> 6);
    const int b0   = blockIdx.x * BT;

    const int c_begin = blockIdx.y * CPG;
    const int c_end   = (c_begin + CPG < NCHUNKS) ? (c_begin + CPG) : NCHUNKS;

    __shared__ float cam_lds[CAMD][BT];     // 10240 B, transposed camera tile
    __shared__ float obuf[HROWS * LSTRIDE]; // 12800 B output transpose buffer

    // stage camera transposed: thread t owns row t (float2 x5, coalesced)
    {
        const float2* c2 = (const float2*)(camera + (size_t)(b0 + tid) * CAMD);
#pragma unroll
        for (int i = 0; i < CAMD / 2; ++i) {
            float2 v = c2[i];
            cam_lds[2 * i][tid]     = v.x;
            cam_lds[2 * i + 1][tid] = v.y;
        }
    }

    // prefetch prior gather for the first chunk (clamped index; clamped
    // lanes' values are never used)
    float pr0, pr1, pr2, pr3;
    {
        const int n0 = c_begin * NETS_PER_CHUNK + wave;
        const int nc = n0 < NN ? n0 : NN - 1;
        pr0 = prior[(size_t)(b0 + 0 * 64 + lane) * NN + nc];
        pr1 = prior[(size_t)(b0 + 1 * 64 + lane) * NN + nc];
        pr2 = prior[(size_t)(b0 + 2 * 64 + lane) * NN + nc];
        pr3 = prior[(size_t)(b0 + 3 * 64 + lane) * NN + nc];
    }

    lds_barrier();   // camera tile visible to all waves

    for (int c = c_begin; c < c_end; ++c) {
        const int n   = c * NETS_PER_CHUNK + wave;   // wave-uniform
        const bool act = (n < NN);
        const int nc  = act ? n : NN - 1;

        const float* __restrict__ w1 = W1 + (size_t)nc * (CAMD + 1) * HD;
        const float* __restrict__ p1 = b1 + (size_t)nc * HD;
        const float* __restrict__ w2 = W2 + (size_t)nc * HD * HD;
        const float* __restrict__ p2 = b2 + (size_t)nc * HD;
        const float* __restrict__ w3 = W3 + (size_t)nc * HD * LODD;
        const float* __restrict__ p3 = b3 + (size_t)nc * LODD;

        // issue NEXT chunk's prior gather now; latency hides under compute
        // (no barrier below drains vmcnt)
        float prn0 = pr0, prn1 = pr1, prn2 = pr2, prn3 = pr3;
        if (c + 1 < c_end) {
            const int n1 = (c + 1) * NETS_PER_CHUNK + wave;
            const int nx = n1 < NN ? n1 : NN - 1;
            prn0 = prior[(size_t)(b0 + 0 * 64 + lane) * NN + nx];
            prn1 = prior[(size_t)(b0 + 1 * 64 + lane) * NN + nx];
            prn2 = prior[(size_t)(b0 + 2 * 64 + lane) * NN + nx];
            prn3 = prior[(size_t)(b0 + 3 * 64 + lane) * NN + nx];
        }

        const int rem = NN - c * NETS_PER_CHUNK;
        const int nv  = rem < NETS_PER_CHUNK ? rem : NETS_PER_CHUNK;

        // rolled sub-tile loop: ONE row's MLP per iteration (inner loops
        // unrolled -> static reg indices; live set ~55 VGPRs, no spill)
#pragma unroll 1
        for (int s = 0; s < SUB; ++s) {
            if (act) {
                const int row = s * 64 + lane;
                const float prs = (s == 0) ? pr0 : (s == 1) ? pr1
                                  : (s == 2) ? pr2 : pr3;

                float cv[CAMD];
#pragma unroll
                for (int i = 0; i < CAMD; ++i)
                    cv[i] = cam_lds[i][row];          // conflict-free b32

                // ---- layer 1 ----
                float h1[HD];
#pragma unroll
                for (int j = 0; j < HD; ++j)
                    h1[j] = fmaf(prs, w1[j], p1[j]);
#pragma unroll
                for (int i = 0; i < CAMD; ++i)
#pragma unroll
                    for (int j = 0; j < HD; ++j)
                        h1[j] = fmaf(cv[i], w1[(i + 1) * HD + j], h1[j]);
#pragma unroll
                for (int j = 0; j < HD; ++j)
                    h1[j] = fmaxf(h1[j], 0.0f);

                // ---- layer 2 ----
                float h2[HD];
#pragma unroll
                for (int k = 0; k < HD; ++k)
                    h2[k] = p2[k];
#pragma unroll
                for (int j = 0; j < HD; ++j)
#pragma unroll
                    for (int k = 0; k < HD; ++k)
                        h2[k] = fmaf(h1[j], w2[j * HD + k], h2[k]);
#pragma unroll
                for (int k = 0; k < HD; ++k)
                    h2[k] = fmaxf(h2[k], 0.0f);

                // ---- layer 3 ----
                float o[LODD];
#pragma unroll
                for (int m = 0; m < LODD; ++m)
                    o[m] = p3[m];
#pragma unroll
                for (int j = 0; j < HD; ++j)
#pragma unroll
                    for (int m = 0; m < LODD; ++m)
                        o[m] = fmaf(h2[j], w3[j * LODD + m], o[m]);

                // stash into half-buffer: local row = (s&1)*64 + lane
                const int lrow = (s & 1) * 64 + lane;
#pragma unroll
                for (int m = 0; m < LODD; ++m)
                    obuf[lrow * LSTRIDE + wave * LODD + m] = o[m];
            }

            if (s & 1) {                 // half-buffer full -> flush
                lds_barrier();
                const int h = s >> 1;
                if (nv == NETS_PER_CHUNK) {
                    for (int f = tid; f < HROWS * 6; f += 256) {
                        const int row  = f / 6;          // compile-time div
                        const int colq = f - row * 6;
                        const float* sp = obuf + row * LSTRIDE + colq * 4;
                        float4 v = make_float4(sp[0], sp[1], sp[2], sp[3]);
                        *(float4*)(out + (size_t)(b0 + h * HROWS + row) * ROWF
                                   + c * (NETS_PER_CHUNK * LODD) + colq * 4) = v;
                    }
                } else {                 // last chunk: nv = 2 -> nq = 3
                    for (int f = tid; f < HROWS * 3; f += 256) {
                        const int row  = f / 3;
                        const int colq = f - row * 3;
                        const float* sp = obuf + row * LSTRIDE + colq * 4;
                        float4 v = make_float4(sp[0], sp[1], sp[2], sp[3]);
                        *(float4*)(out + (size_t)(b0 + h * HROWS + row) * ROWF
                                   + c * (NETS_PER_CHUNK * LODD) + colq * 4) = v;
                    }
                }
                lds_barrier();           // flush reads done before re-stash
            }
        }

        pr0 = prn0; pr1 = prn1; pr2 = prn2; pr3 = prn3;
    }
}

extern "C" void kernel_launch(void* const* d_in, const int* in_sizes, int n_in,
                              void* d_out, int out_size, void* d_ws, size_t ws_size,
                              hipStream_t stream) {
    const float* prior  = (const float*)d_in[0];
    const float* camera = (const float*)d_in[1];
    const float* W1     = (const float*)d_in[2];
    const float* b1     = (const float*)d_in[3];
    const float* W2     = (const float*)d_in[4];
    const float* b2     = (const float*)d_in[5];
    const float* W3     = (const float*)d_in[6];
    const float* b3     = (const float*)d_in[7];
    float* out = (float*)d_out;

    dim3 grid(8192 / BT, NGROUPS);   // 32 x 91 = 2912 blocks
    dim3 block(256);
    Net_18966575579675_kernel<<<grid, block, 0, stream>>>(
        prior, camera, W1, b1, W2, b2, W3, b3, out);
}